// Round 7
// baseline (286.209 us; speedup 1.0000x reference)
//
#include <hip/hip_runtime.h>
#include <hip/hip_bf16.h>
#include <stdint.h>

// exp(s/sqrt(128)) = exp2(s * log2(e)/sqrt(128)); folded into Q at k_qk epilogue
#define SCALE_LOG2E 0.12751743f

typedef __bf16 bf16x8 __attribute__((ext_vector_type(8)));
typedef float floatx4 __attribute__((ext_vector_type(4)));
typedef uint32_t u32x4v __attribute__((ext_vector_type(4)));

__device__ __forceinline__ bf16x8 load_bf8(const void* p) {
    u32x4v v = *(const u32x4v*)p;
    return __builtin_bit_cast(bf16x8, v);
}

__device__ __forceinline__ bf16x8 cvt8(float4 u, float4 v) {
    union { bf16x8 v8; __hip_bfloat16 h[8]; } r;
    r.h[0] = __float2bfloat16(u.x); r.h[1] = __float2bfloat16(u.y);
    r.h[2] = __float2bfloat16(u.z); r.h[3] = __float2bfloat16(u.w);
    r.h[4] = __float2bfloat16(v.x); r.h[5] = __float2bfloat16(v.y);
    r.h[6] = __float2bfloat16(v.z); r.h[7] = __float2bfloat16(v.w);
    return r.v8;
}

// async 16B global -> LDS DMA (no VGPR destination; compiler cannot collapse)
__device__ __forceinline__ void dma16(const void* g, void* l) {
    __builtin_amdgcn_global_load_lds(
        (const __attribute__((address_space(1))) uint32_t*)g,
        (__attribute__((address_space(3))) uint32_t*)l, 16, 0, 0);
}

// ---------------------------------------------------------------------------
// Kernel A: cvt w_q,w_k -> bf16 (b<96); c[768] = w_o @ w_v (b 96..98);
// zero num/den (b 99..131; 16384 contiguous floats in ws).
// ---------------------------------------------------------------------------
__global__ void k_prep(const float* __restrict__ w_q, const float* __restrict__ w_k,
                       const float* __restrict__ w_v, const float* __restrict__ w_o,
                       __hip_bfloat16* __restrict__ wq_bf,
                       __hip_bfloat16* __restrict__ wk_bf,
                       float* __restrict__ c_out,
                       float* __restrict__ numden) {
    int b = blockIdx.x;
    int t = threadIdx.x;
    if (b < 96) {
        #pragma unroll
        for (int p = 0; p < 8; ++p) {
            int i = b * 2048 + p * 256 + t;
            if (i < 98304) wq_bf[i] = __float2bfloat16(w_q[i]);
            else           wk_bf[i - 98304] = __float2bfloat16(w_k[i - 98304]);
        }
    } else if (b < 99) {
        int j = (b - 96) * 256 + t;
        float acc = 0.f;
        #pragma unroll 8
        for (int k = 0; k < 64; ++k) acc += w_o[k] * w_v[k * 768 + j];
        c_out[j] = acc;
    } else {
        int z = (b - 99) * 512 + t * 2;
        if (z < 16384) { numden[z] = 0.f; numden[z + 1] = 0.f; }
    }
}

// ---------------------------------------------------------------------------
// Kernel B (unchanged — control): Q = x1 @ w_q^T * SCALE (bid 0..255),
// K = x2 @ w_k^T (256..511), vs = x2 . c (bid 512..767).
// m97-style global_load_lds double-buffered A-tile, XOR-swizzled chunks.
// ---------------------------------------------------------------------------
__global__ __launch_bounds__(256, 4) void k_qk(
        const float* __restrict__ x1, const float* __restrict__ x2,
        const __hip_bfloat16* __restrict__ wq_bf,
        const __hip_bfloat16* __restrict__ wk_bf,
        const float* __restrict__ c_in,
        __hip_bfloat16* __restrict__ Qb, __hip_bfloat16* __restrict__ Kb,
        float* __restrict__ vs_g) {
    __shared__ alignas(16) float sA[2][32 * 128];  // 2 x 16 KB, swizzled 16B chunks

    int bid = blockIdx.x;
    int t = threadIdx.x;

    if (bid >= 512) {
        // ---- vs blocks: 256 blocks x 32 rows, 8 threads per row ----
        int vb = bid - 512;
        int r = vb * 32 + (t >> 3), h = t & 7;
        const float* xr = x2 + (size_t)r * 768 + h * 96;
        const float* cr = c_in + h * 96;
        float vacc = 0.f;
        #pragma unroll 6
        for (int j = 0; j < 96; j += 4) {
            float4 v = *(const float4*)(xr + j);
            vacc += v.x * cr[j] + v.y * cr[j + 1] + v.z * cr[j + 2] + v.w * cr[j + 3];
        }
        vacc += __shfl_xor(vacc, 1, 64);
        vacc += __shfl_xor(vacc, 2, 64);
        vacc += __shfl_xor(vacc, 4, 64);
        if (h == 0) vs_g[r] = vacc;
        return;
    }

    bool isK = bid >= 256;
    int row0 = (bid & 255) * 32;
    const float* x = isK ? x2 : x1;
    const __hip_bfloat16* w = isK ? wk_bf : wq_bf;
    __hip_bfloat16* outp = isK ? Kb : Qb;

    int wave = t >> 6, lane = t & 63;
    int m = lane & 15, quad = lane >> 4;
    int col0 = wave * 32;

    const float* gsrc[4];
    #pragma unroll
    for (int p = 0; p < 4; ++p) {
        int s = wave * 256 + p * 64 + lane;
        int r = s >> 5, pos = s & 31;
        int c = pos ^ (r & 7);
        gsrc[p] = x + (size_t)(row0 + r) * 768 + c * 4;
    }
    auto dma_tile = [&](int buf, int kc) {
        #pragma unroll
        for (int p = 0; p < 4; ++p)
            dma16(gsrc[p] + kc, &sA[buf][(wave * 256 + p * 64) * 4]);
    };

    const __hip_bfloat16* bp = w + (size_t)(col0 + m) * 768 + quad * 8;

    floatx4 acc[2][2];
    #pragma unroll
    for (int i = 0; i < 2; ++i)
        #pragma unroll
        for (int j = 0; j < 2; ++j) acc[i][j] = {0.f, 0.f, 0.f, 0.f};

    dma_tile(0, 0);

    for (int it = 0; it < 6; ++it) {
        __syncthreads();
        if (it < 5) dma_tile((it + 1) & 1, (it + 1) * 128);

        const float* A = sA[it & 1];
        int kc = it * 128;
        #pragma unroll
        for (int ks = 0; ks < 4; ++ks) {
            bf16x8 afr[2], bfr[2];
            #pragma unroll
            for (int i = 0; i < 2; ++i) {
                int r = i * 16 + m;
                int cb = ks * 8 + quad * 2;
                int p0 = cb ^ (r & 7), p1 = (cb + 1) ^ (r & 7);
                float4 f0 = *(const float4*)&A[r * 128 + p0 * 4];
                float4 f1 = *(const float4*)&A[r * 128 + p1 * 4];
                afr[i] = cvt8(f0, f1);
            }
            #pragma unroll
            for (int j = 0; j < 2; ++j)
                bfr[j] = load_bf8(bp + (size_t)j * 16 * 768 + kc + ks * 32);
            #pragma unroll
            for (int i = 0; i < 2; ++i)
                #pragma unroll
                for (int j = 0; j < 2; ++j)
                    acc[i][j] = __builtin_amdgcn_mfma_f32_16x16x32_bf16(afr[i], bfr[j], acc[i][j], 0, 0, 0);
        }
    }

    float cscale = isK ? 1.0f : SCALE_LOG2E;
    #pragma unroll
    for (int i = 0; i < 2; ++i)
        #pragma unroll
        for (int j = 0; j < 2; ++j)
            #pragma unroll
            for (int r = 0; r < 4; ++r) {
                int row = row0 + i * 16 + quad * 4 + r;
                int col = col0 + j * 16 + m;
                outp[(size_t)row * 128 + col] = __float2bfloat16(acc[i][j][r] * cscale);
            }
}

// ---------------------------------------------------------------------------
// Kernel C: flash-style attention row-sums, rebuilt for 4 blocks/CU.
// grid 1024 = 64 q-blocks x 16 t-chunks of 512. Block = 128 q x 512 t;
// wave = 32 q-rows x full 64-t iter tile. K tile 64x128 staged via kreg
// prefetch + padded ds_write (LDK=136, proven R5 pattern). VGPR ~110 so
// __launch_bounds__(256,4) holds -> 16 waves/CU; barrier stalls of one
// block overlap with 3 other resident blocks.
// ---------------------------------------------------------------------------
__global__ __launch_bounds__(256, 4) void k_attn(
        const __hip_bfloat16* __restrict__ Qb, const __hip_bfloat16* __restrict__ Kb,
        const float* __restrict__ vs_g,
        float* __restrict__ num_g, float* __restrict__ den_g) {
    constexpr int LDK = 136;  // 128 + 8 pad
    __shared__ alignas(16) __hip_bfloat16 sK[64 * LDK];  // 17408 B
    __shared__ float sVS[512];

    int bid = blockIdx.x;
    int qb = bid >> 4, tc = bid & 15;
    int q0 = qb * 128, t0 = tc * 512;

    int t = threadIdx.x;
    int wave = t >> 6, lane = t & 63;
    int m = lane & 15, quad = lane >> 4;

    // Q fragments (loop-invariant): wave's 32 q-rows, A[m][k=quad*8+j]
    bf16x8 qf[4][2];
    #pragma unroll
    for (int i = 0; i < 2; ++i)
        #pragma unroll
        for (int kk = 0; kk < 4; ++kk)
            qf[kk][i] = load_bf8(Qb + (size_t)(q0 + wave * 32 + i * 16 + m) * 128 + kk * 32 + quad * 8);

    #pragma unroll
    for (int p = 0; p < 2; ++p) sVS[p * 256 + t] = vs_g[t0 + p * 256 + t];

    // K staging: 64 rows x 16 chunks(16B) = 1024 slots, 4 per thread
    u32x4v kreg[4];
    #pragma unroll
    for (int p = 0; p < 4; ++p) {
        int s = p * 256 + t;
        int r = s >> 4, c = (s & 15) * 8;
        kreg[p] = *(const u32x4v*)(Kb + (size_t)(t0 + r) * 128 + c);
    }

    float num_acc[2][4], den_acc[2][4];
    #pragma unroll
    for (int i = 0; i < 2; ++i)
        #pragma unroll
        for (int r = 0; r < 4; ++r) { num_acc[i][r] = 0.f; den_acc[i][r] = 0.f; }

    for (int it = 0; it < 8; ++it) {
        __syncthreads();                  // prev iter's sK reads done
        #pragma unroll
        for (int p = 0; p < 4; ++p) {
            int s = p * 256 + t;
            int r = s >> 4, c = (s & 15) * 8;
            *(u32x4v*)(&sK[r * LDK + c]) = kreg[p];
        }
        __syncthreads();
        if (it < 7) {
            #pragma unroll
            for (int p = 0; p < 4; ++p) {
                int s = p * 256 + t;
                int r = s >> 4, c = (s & 15) * 8;
                kreg[p] = *(const u32x4v*)(Kb + (size_t)(t0 + (it + 1) * 64 + r) * 128 + c);
            }
        }

        // jh-split keeps live acc at 16 VGPR (fits the 128-cap with room)
        #pragma unroll
        for (int jh = 0; jh < 2; ++jh) {
            floatx4 acc[2][2];
            #pragma unroll
            for (int i = 0; i < 2; ++i)
                #pragma unroll
                for (int j = 0; j < 2; ++j) acc[i][j] = {0.f, 0.f, 0.f, 0.f};

            #pragma unroll
            for (int kk = 0; kk < 4; ++kk) {
                bf16x8 bfr[2];
                #pragma unroll
                for (int j = 0; j < 2; ++j)
                    bfr[j] = load_bf8(&sK[((jh * 2 + j) * 16 + m) * LDK + kk * 32 + quad * 8]);
                #pragma unroll
                for (int i = 0; i < 2; ++i)
                    #pragma unroll
                    for (int j = 0; j < 2; ++j)
                        acc[i][j] = __builtin_amdgcn_mfma_f32_16x16x32_bf16(qf[kk][i], bfr[j], acc[i][j], 0, 0, 0);
            }
            #pragma unroll
            for (int j = 0; j < 2; ++j) {
                float vsv = sVS[it * 64 + (jh * 2 + j) * 16 + m];
                #pragma unroll
                for (int i = 0; i < 2; ++i)
                    #pragma unroll
                    for (int r = 0; r < 4; ++r) {
                        float p = __builtin_amdgcn_exp2f(acc[i][j][r]);
                        den_acc[i][r] += p;
                        num_acc[i][r] += p * vsv;
                    }
            }
        }
    }

    #pragma unroll
    for (int i = 0; i < 2; ++i)
        #pragma unroll
        for (int r = 0; r < 4; ++r) {
            float n = num_acc[i][r], d = den_acc[i][r];
            #pragma unroll
            for (int mask = 1; mask <= 8; mask <<= 1) {
                n += __shfl_xor(n, mask, 64);
                d += __shfl_xor(d, mask, 64);
            }
            if ((lane & 15) == 0) {
                int row = q0 + wave * 32 + i * 16 + quad * 4 + r;
                atomicAdd(&num_g[row], n);
                atomicAdd(&den_g[row], d);
            }
        }
}

// ---------------------------------------------------------------------------
// Kernel D: gated = x1 * (1 - num/den). float4 grid-mapped, memory-bound.
// ---------------------------------------------------------------------------
__global__ void k_final(const float* __restrict__ x1,
                        const float* __restrict__ num_g,
                        const float* __restrict__ den_g,
                        float* __restrict__ outp) {
    int idx = blockIdx.x * 256 + threadIdx.x;  // float4 index, 192 per row
    int s = idx / 192;
    float4 v = *(const float4*)(x1 + (size_t)idx * 4);
    float g = 1.0f - num_g[s] / den_g[s];
    float4 rv;
    rv.x = v.x * g; rv.y = v.y * g; rv.z = v.z * g; rv.w = v.w * g;
    *(float4*)(outp + (size_t)idx * 4) = rv;
}

// ---------------------------------------------------------------------------
extern "C" void kernel_launch(void* const* d_in, const int* in_sizes, int n_in,
                              void* d_out, int out_size, void* d_ws, size_t ws_size,
                              hipStream_t stream) {
    const float* x1  = (const float*)d_in[0];
    const float* x2  = (const float*)d_in[1];
    const float* w_q = (const float*)d_in[2];
    const float* w_k = (const float*)d_in[3];
    const float* w_v = (const float*)d_in[4];
    const float* w_o = (const float*)d_in[5];
    float* outp = (float*)d_out;

    char* ws = (char*)d_ws;
    __hip_bfloat16* wq_bf = (__hip_bfloat16*)(ws + 0);        // 196608 B
    __hip_bfloat16* wk_bf = (__hip_bfloat16*)(ws + 196608);   // 196608 B
    float* c_buf          = (float*)(ws + 393216);            // 3072 B
    __hip_bfloat16* Qb    = (__hip_bfloat16*)(ws + 396288);   // 2 MB
    __hip_bfloat16* Kb    = (__hip_bfloat16*)(ws + 2493440);  // 2 MB
    float* vs_g           = (float*)(ws + 4590592);           // 32 KB
    float* num_g          = (float*)(ws + 4623360);           // 32 KB
    float* den_g          = (float*)(ws + 4656128);           // 32 KB (contig after num_g)

    k_prep<<<132, 256, 0, stream>>>(w_q, w_k, w_v, w_o, wq_bf, wk_bf, c_buf, num_g);
    k_qk<<<768, 256, 0, stream>>>(x1, x2, wq_bf, wk_bf, c_buf, Qb, Kb, vs_g);
    k_attn<<<1024, 256, 0, stream>>>(Qb, Kb, vs_g, num_g, den_g);
    k_final<<<6144, 256, 0, stream>>>(x1, num_g, den_g, outp);
}

// Round 8
// 181.270 us; speedup vs baseline: 1.5789x; 1.5789x over previous
//
#include <hip/hip_runtime.h>
#include <hip/hip_bf16.h>
#include <stdint.h>

// exp(s/sqrt(128)) = exp2(s * log2(e)/sqrt(128)); folded into Q at k_qk epilogue
#define SCALE_LOG2E 0.12751743f

typedef __bf16 bf16x8 __attribute__((ext_vector_type(8)));
typedef float floatx4 __attribute__((ext_vector_type(4)));
typedef uint32_t u32x4v __attribute__((ext_vector_type(4)));

__device__ __forceinline__ bf16x8 load_bf8(const void* p) {
    u32x4v v = *(const u32x4v*)p;
    return __builtin_bit_cast(bf16x8, v);
}

__device__ __forceinline__ bf16x8 cvt8(float4 u, float4 v) {
    union { bf16x8 v8; __hip_bfloat16 h[8]; } r;
    r.h[0] = __float2bfloat16(u.x); r.h[1] = __float2bfloat16(u.y);
    r.h[2] = __float2bfloat16(u.z); r.h[3] = __float2bfloat16(u.w);
    r.h[4] = __float2bfloat16(v.x); r.h[5] = __float2bfloat16(v.y);
    r.h[6] = __float2bfloat16(v.z); r.h[7] = __float2bfloat16(v.w);
    return r.v8;
}

// async 16B global -> LDS DMA (no VGPR destination; compiler cannot collapse)
__device__ __forceinline__ void dma16(const void* g, void* l) {
    __builtin_amdgcn_global_load_lds(
        (const __attribute__((address_space(1))) uint32_t*)g,
        (__attribute__((address_space(3))) uint32_t*)l, 16, 0, 0);
}

// ---------------------------------------------------------------------------
// Kernel A: cvt w_q,w_k -> bf16 (b<96); c[768] = w_o @ w_v (b 96..98);
// zero num/den (b 99..131; 16384 contiguous floats in ws).
// ---------------------------------------------------------------------------
__global__ void k_prep(const float* __restrict__ w_q, const float* __restrict__ w_k,
                       const float* __restrict__ w_v, const float* __restrict__ w_o,
                       __hip_bfloat16* __restrict__ wq_bf,
                       __hip_bfloat16* __restrict__ wk_bf,
                       float* __restrict__ c_out,
                       float* __restrict__ numden) {
    int b = blockIdx.x;
    int t = threadIdx.x;
    if (b < 96) {
        #pragma unroll
        for (int p = 0; p < 8; ++p) {
            int i = b * 2048 + p * 256 + t;
            if (i < 98304) wq_bf[i] = __float2bfloat16(w_q[i]);
            else           wk_bf[i - 98304] = __float2bfloat16(w_k[i - 98304]);
        }
    } else if (b < 99) {
        int j = (b - 96) * 256 + t;
        float acc = 0.f;
        #pragma unroll 8
        for (int k = 0; k < 64; ++k) acc += w_o[k] * w_v[k * 768 + j];
        c_out[j] = acc;
    } else {
        int z = (b - 99) * 512 + t * 2;
        if (z < 16384) { numden[z] = 0.f; numden[z + 1] = 0.f; }
    }
}

// ---------------------------------------------------------------------------
// Kernel B (unchanged — control): Q = x1 @ w_q^T * SCALE (bid 0..255),
// K = x2 @ w_k^T (256..511), vs = x2 . c (bid 512..767).
// m97-style global_load_lds double-buffered A-tile, XOR-swizzled chunks.
// ---------------------------------------------------------------------------
__global__ __launch_bounds__(256, 4) void k_qk(
        const float* __restrict__ x1, const float* __restrict__ x2,
        const __hip_bfloat16* __restrict__ wq_bf,
        const __hip_bfloat16* __restrict__ wk_bf,
        const float* __restrict__ c_in,
        __hip_bfloat16* __restrict__ Qb, __hip_bfloat16* __restrict__ Kb,
        float* __restrict__ vs_g) {
    __shared__ alignas(16) float sA[2][32 * 128];  // 2 x 16 KB, swizzled 16B chunks

    int bid = blockIdx.x;
    int t = threadIdx.x;

    if (bid >= 512) {
        // ---- vs blocks: 256 blocks x 32 rows, 8 threads per row ----
        int vb = bid - 512;
        int r = vb * 32 + (t >> 3), h = t & 7;
        const float* xr = x2 + (size_t)r * 768 + h * 96;
        const float* cr = c_in + h * 96;
        float vacc = 0.f;
        #pragma unroll 6
        for (int j = 0; j < 96; j += 4) {
            float4 v = *(const float4*)(xr + j);
            vacc += v.x * cr[j] + v.y * cr[j + 1] + v.z * cr[j + 2] + v.w * cr[j + 3];
        }
        vacc += __shfl_xor(vacc, 1, 64);
        vacc += __shfl_xor(vacc, 2, 64);
        vacc += __shfl_xor(vacc, 4, 64);
        if (h == 0) vs_g[r] = vacc;
        return;
    }

    bool isK = bid >= 256;
    int row0 = (bid & 255) * 32;
    const float* x = isK ? x2 : x1;
    const __hip_bfloat16* w = isK ? wk_bf : wq_bf;
    __hip_bfloat16* outp = isK ? Kb : Qb;

    int wave = t >> 6, lane = t & 63;
    int m = lane & 15, quad = lane >> 4;
    int col0 = wave * 32;

    const float* gsrc[4];
    #pragma unroll
    for (int p = 0; p < 4; ++p) {
        int s = wave * 256 + p * 64 + lane;
        int r = s >> 5, pos = s & 31;
        int c = pos ^ (r & 7);
        gsrc[p] = x + (size_t)(row0 + r) * 768 + c * 4;
    }
    auto dma_tile = [&](int buf, int kc) {
        #pragma unroll
        for (int p = 0; p < 4; ++p)
            dma16(gsrc[p] + kc, &sA[buf][(wave * 256 + p * 64) * 4]);
    };

    const __hip_bfloat16* bp = w + (size_t)(col0 + m) * 768 + quad * 8;

    floatx4 acc[2][2];
    #pragma unroll
    for (int i = 0; i < 2; ++i)
        #pragma unroll
        for (int j = 0; j < 2; ++j) acc[i][j] = {0.f, 0.f, 0.f, 0.f};

    dma_tile(0, 0);

    for (int it = 0; it < 6; ++it) {
        __syncthreads();
        if (it < 5) dma_tile((it + 1) & 1, (it + 1) * 128);

        const float* A = sA[it & 1];
        int kc = it * 128;
        #pragma unroll
        for (int ks = 0; ks < 4; ++ks) {
            bf16x8 afr[2], bfr[2];
            #pragma unroll
            for (int i = 0; i < 2; ++i) {
                int r = i * 16 + m;
                int cb = ks * 8 + quad * 2;
                int p0 = cb ^ (r & 7), p1 = (cb + 1) ^ (r & 7);
                float4 f0 = *(const float4*)&A[r * 128 + p0 * 4];
                float4 f1 = *(const float4*)&A[r * 128 + p1 * 4];
                afr[i] = cvt8(f0, f1);
            }
            #pragma unroll
            for (int j = 0; j < 2; ++j)
                bfr[j] = load_bf8(bp + (size_t)j * 16 * 768 + kc + ks * 32);
            #pragma unroll
            for (int i = 0; i < 2; ++i)
                #pragma unroll
                for (int j = 0; j < 2; ++j)
                    acc[i][j] = __builtin_amdgcn_mfma_f32_16x16x32_bf16(afr[i], bfr[j], acc[i][j], 0, 0, 0);
        }
    }

    float cscale = isK ? 1.0f : SCALE_LOG2E;
    #pragma unroll
    for (int i = 0; i < 2; ++i)
        #pragma unroll
        for (int j = 0; j < 2; ++j)
            #pragma unroll
            for (int r = 0; r < 4; ++r) {
                int row = row0 + i * 16 + quad * 4 + r;
                int col = col0 + j * 16 + m;
                outp[(size_t)row * 128 + col] = __float2bfloat16(acc[i][j][r] * cscale);
            }
}

// ---------------------------------------------------------------------------
// Kernel C: flash-style attention row-sums — LDS-FREE. No barriers, no
// shared state: each wave independently owns 64 q-rows x 256 keys, loading
// K-fragments straight from L2-resident Kb (16B loads, same pattern as the
// validated weight loads in R2's k_qk). Waves free-run; L2 latency hidden by
// ~3 waves/SIMD. launch_bounds(256,1): VGPR cap ~256 so the ~150-reg demand
// (qf 64 + num/den 32 + bfr/acc/addr) fits WITHOUT spill (R7 post-mortem:
// (256,4) capped at 64 and thrashed scratch).
// grid 1024 = 32 q-blocks(256 rows) x 32 t-chunks(256 keys).
// ---------------------------------------------------------------------------
__global__ __launch_bounds__(256, 1) void k_attn(
        const __hip_bfloat16* __restrict__ Qb, const __hip_bfloat16* __restrict__ Kb,
        const float* __restrict__ vs_g,
        float* __restrict__ num_g, float* __restrict__ den_g) {
    int bid = blockIdx.x;
    int qb = bid >> 5, tc = bid & 31;
    int q0 = qb * 256, t0 = tc * 256;

    int t = threadIdx.x;
    int wave = t >> 6, lane = t & 63;
    int m = lane & 15, quad = lane >> 4;
    int qw = q0 + wave * 64;  // this wave's 64 q-rows

    // Q fragments (loop-invariant): A[m][k=quad*8+j] layout, 64 VGPRs
    bf16x8 qf[4][4];
    #pragma unroll
    for (int i = 0; i < 4; ++i)
        #pragma unroll
        for (int kk = 0; kk < 4; ++kk)
            qf[kk][i] = load_bf8(Qb + (size_t)(qw + i * 16 + m) * 128 + kk * 32 + quad * 8);

    float num_acc[4][4], den_acc[4][4];
    #pragma unroll
    for (int i = 0; i < 4; ++i)
        #pragma unroll
        for (int r = 0; r < 4; ++r) { num_acc[i][r] = 0.f; den_acc[i][r] = 0.f; }

    for (int jt = 0; jt < 16; ++jt) {
        int key = t0 + jt * 16 + m;
        const __hip_bfloat16* kp = Kb + (size_t)key * 128 + quad * 8;

        bf16x8 bfr[4];
        #pragma unroll
        for (int kk = 0; kk < 4; ++kk) bfr[kk] = load_bf8(kp + kk * 32);
        float vsv = vs_g[key];

        floatx4 acc[4];
        #pragma unroll
        for (int i = 0; i < 4; ++i) acc[i] = {0.f, 0.f, 0.f, 0.f};

        #pragma unroll
        for (int kk = 0; kk < 4; ++kk)
            #pragma unroll
            for (int i = 0; i < 4; ++i)
                acc[i] = __builtin_amdgcn_mfma_f32_16x16x32_bf16(qf[kk][i], bfr[kk], acc[i], 0, 0, 0);

        #pragma unroll
        for (int i = 0; i < 4; ++i)
            #pragma unroll
            for (int r = 0; r < 4; ++r) {
                float p = __builtin_amdgcn_exp2f(acc[i][r]);
                den_acc[i][r] += p;
                num_acc[i][r] += p * vsv;
            }
    }

    // reduce across the 16 lanes of each quad-group, then one atomic per row
    #pragma unroll
    for (int i = 0; i < 4; ++i)
        #pragma unroll
        for (int r = 0; r < 4; ++r) {
            float n = num_acc[i][r], d = den_acc[i][r];
            #pragma unroll
            for (int mask = 1; mask <= 8; mask <<= 1) {
                n += __shfl_xor(n, mask, 64);
                d += __shfl_xor(d, mask, 64);
            }
            if ((lane & 15) == 0) {
                int row = qw + i * 16 + quad * 4 + r;
                atomicAdd(&num_g[row], n);
                atomicAdd(&den_g[row], d);
            }
        }
}

// ---------------------------------------------------------------------------
// Kernel D: gated = x1 * (1 - num/den). float4 grid-mapped, memory-bound.
// ---------------------------------------------------------------------------
__global__ void k_final(const float* __restrict__ x1,
                        const float* __restrict__ num_g,
                        const float* __restrict__ den_g,
                        float* __restrict__ outp) {
    int idx = blockIdx.x * 256 + threadIdx.x;  // float4 index, 192 per row
    int s = idx / 192;
    float4 v = *(const float4*)(x1 + (size_t)idx * 4);
    float g = 1.0f - num_g[s] / den_g[s];
    float4 rv;
    rv.x = v.x * g; rv.y = v.y * g; rv.z = v.z * g; rv.w = v.w * g;
    *(float4*)(outp + (size_t)idx * 4) = rv;
}

// ---------------------------------------------------------------------------
extern "C" void kernel_launch(void* const* d_in, const int* in_sizes, int n_in,
                              void* d_out, int out_size, void* d_ws, size_t ws_size,
                              hipStream_t stream) {
    const float* x1  = (const float*)d_in[0];
    const float* x2  = (const float*)d_in[1];
    const float* w_q = (const float*)d_in[2];
    const float* w_k = (const float*)d_in[3];
    const float* w_v = (const float*)d_in[4];
    const float* w_o = (const float*)d_in[5];
    float* outp = (float*)d_out;

    char* ws = (char*)d_ws;
    __hip_bfloat16* wq_bf = (__hip_bfloat16*)(ws + 0);        // 196608 B
    __hip_bfloat16* wk_bf = (__hip_bfloat16*)(ws + 196608);   // 196608 B
    float* c_buf          = (float*)(ws + 393216);            // 3072 B
    __hip_bfloat16* Qb    = (__hip_bfloat16*)(ws + 396288);   // 2 MB
    __hip_bfloat16* Kb    = (__hip_bfloat16*)(ws + 2493440);  // 2 MB
    float* vs_g           = (float*)(ws + 4590592);           // 32 KB
    float* num_g          = (float*)(ws + 4623360);           // 32 KB
    float* den_g          = (float*)(ws + 4656128);           // 32 KB (contig after num_g)

    k_prep<<<132, 256, 0, stream>>>(w_q, w_k, w_v, w_o, wq_bf, wk_bf, c_buf, num_g);
    k_qk<<<768, 256, 0, stream>>>(x1, x2, wq_bf, wk_bf, c_buf, Qb, Kb, vs_g);
    k_attn<<<1024, 256, 0, stream>>>(Qb, Kb, vs_g, num_g, den_g);
    k_final<<<6144, 256, 0, stream>>>(x1, num_g, den_g, outp);
}